// Round 1
// baseline (29106.567 us; speedup 1.0000x reference)
//
#include <hip/hip_runtime.h>
#include <hip/hip_bf16.h>

// ---------------------------------------------------------------------------
// GRU_44513041056013 on MI355X.
// Structure:
//   k_pack_wo : Wo fp32 [1024][32000] -> bf16 packed in MFMA B-fragment order
//   k_embed   : emb gather -> embs bf16 [T][B][E]
//   k_rnn     : persistent kernel, 192 blocks (1/CU). Each block owns two
//               16-col weight tiles (bf16, resident in LDS all 256 steps).
//               4 phases/step, custom device-scope grid barrier.
//               Master h state fp32; MFMA inputs bf16.
//   k_out     : [4096,1024]@[1024,32000] bf16 MFMA GEMM + bias, fp32 out.
// ---------------------------------------------------------------------------

#define B_   16
#define T_   256
#define S_   1024
#define E_   1024
#define K2_  2048
#define V_   32000
#define NBLK 192
#define NTHR 256

typedef __attribute__((ext_vector_type(8))) short bf16x8;
typedef __attribute__((ext_vector_type(4))) float f32x4;

__device__ __forceinline__ unsigned short f2bf(float f) {
  unsigned u = __builtin_bit_cast(unsigned, f);
  unsigned r = (u + 0x7FFFu + ((u >> 16) & 1u)) >> 16;   // RNE
  return (unsigned short)r;
}

// --- Wo packer: slot s = ((ntile*32 + kb)*64 + lane), 8 bf16 per slot.
// elem j <-> Wo[kb*32 + (lane>>4)*8 + j][ntile*16 + (lane&15)]
__global__ void k_pack_wo(const float* __restrict__ Wo,
                          unsigned short* __restrict__ pk) {
  int s = blockIdx.x * 256 + threadIdx.x;          // 2000*32*64 = 4,096,000 slots
  int lane  = s & 63;
  int kb    = (s >> 6) & 31;
  int ntile = s >> 11;
  int n  = ntile * 16 + (lane & 15);
  int k0 = kb * 32 + ((lane >> 4) << 3);
  unsigned short tmp[8];
#pragma unroll
  for (int j = 0; j < 8; j++)
    tmp[j] = f2bf(Wo[(size_t)(k0 + j) * V_ + n]);
  *(bf16x8*)(pk + (size_t)s * 8) = *(bf16x8*)tmp;
}

// --- embedding gather: embs[t][b][e] = bf16(emb[x[b][t]][e])
__global__ void k_embed(const int* __restrict__ x, const float* __restrict__ emb,
                        unsigned short* __restrict__ embs) {
  int i4 = blockIdx.x * 256 + threadIdx.x;          // handles 4 elems; 1,048,576 total
  int e  = (i4 * 4) & (E_ - 1);
  int bt = (i4 * 4) >> 10;                          // t*16 + b
  int b = bt & 15, t = bt >> 4;
  int row = x[b * T_ + t];
  const float* src = emb + (size_t)row * E_ + e;
  unsigned short o[4];
#pragma unroll
  for (int j = 0; j < 4; j++) o[j] = f2bf(src[j]);
  *(unsigned long long*)(embs + (size_t)i4 * 4) = *(unsigned long long*)o;
}

// --- persistent GRU recurrence -------------------------------------------
// Tile ids g=0..383: [z0:0-63 | r0:64-127 | n0:128-191 | z1:192-255 |
// r1:256-319 | n1:320-383]; block bid owns {2bid, 2bid+1} (never straddles).
// Phases: 0 = z0,r0   1 = n0 (+h0 update)   2 = z1,r1   3 = n1 (+h1, hist)
__global__ void __launch_bounds__(NTHR, 1) k_rnn(
    const float* __restrict__ Wz, const float* __restrict__ Wr, const float* __restrict__ Wn,
    const float* __restrict__ bz, const float* __restrict__ br, const float* __restrict__ bn,
    const unsigned short* __restrict__ embs,
    float* __restrict__ h0, float* __restrict__ h1,
    unsigned short* __restrict__ h0bf, unsigned short* __restrict__ h1bf,
    unsigned short* __restrict__ rh0bf, unsigned short* __restrict__ rh1bf,
    float* __restrict__ z0buf, float* __restrict__ z1buf,
    unsigned short* __restrict__ hist, unsigned* __restrict__ bar,
    float* __restrict__ htail) {
  extern __shared__ char smem[];
  unsigned short* wlds = (unsigned short*)smem;     // 2 tiles * 32768 ushorts (128 KB)
  float* red = (float*)(smem + 131072);             // 4 waves * 64 lanes * f32x4 (4 KB)

  const int tid = threadIdx.x, bid = blockIdx.x;
  const int wv = tid >> 6, lane = tid & 63;
  const int q = lane >> 4, m15 = lane & 15;

  const float* WS[3] = {Wz, Wr, Wn};
  const float* BS[3] = {bz, br, bn};
  int g[2] = {2 * bid, 2 * bid + 1};

  // Stage my two weight tiles into LDS in MFMA B-fragment order (once).
  for (int ts = 0; ts < 2; ts++) {
    int gg = g[ts];
    int mi = gg >> 6;
    int c0 = (gg & 63) << 4;
    const float* Wbase = WS[mi % 3] + (size_t)(mi / 3) * K2_ * S_;
    unsigned short* dst = wlds + ts * 32768;
    for (int k = tid; k < K2_; k += NTHR) {
      const float* srcr = Wbase + (size_t)k * S_ + c0;   // 16 contiguous fp32
      int kb = k >> 5, qq = (k >> 3) & 3, jj = k & 7;
      unsigned short* d2 = dst + kb * 512 + jj;
#pragma unroll
      for (int j16 = 0; j16 < 16; j16++)
        d2[(qq * 16 + j16) * 8] = f2bf(srcr[j16]);
    }
  }
  __syncthreads();

  int mi0 = g[0] >> 6;
  int myphase = (mi0 <= 1) ? 0 : (mi0 == 2 ? 1 : (mi0 <= 4 ? 2 : 3));
  unsigned epoch = 0;

  for (int t = 0; t < T_; t++) {
    const unsigned short* embt = embs + (size_t)t * B_ * E_;
    for (int ph = 0; ph < 4; ph++) {
      if (ph == myphase) {
        const unsigned short *AL, *AR;     // A = [AL (k<1024) | AR (k>=1024)]
        if (ph == 0)      { AL = embt; AR = h0bf;  }
        else if (ph == 1) { AL = embt; AR = rh0bf; }
        else if (ph == 2) { AL = h0bf; AR = h1bf;  }
        else              { AL = h0bf; AR = rh1bf; }
        for (int ts = 0; ts < 2; ts++) {
          int gg = g[ts];
          int mi = gg >> 6, mk = mi % 3, layer = mi / 3;
          int c0 = (gg & 63) << 4;
          f32x4 acc = {0.f, 0.f, 0.f, 0.f};
          // K split across 4 waves (16 kb each); waves 0-1 left half, 2-3 right.
#pragma unroll
          for (int i = 0; i < 16; i++) {
            int kb = wv * 16 + i;
            int k0 = kb * 32;
            const unsigned short* ab = (k0 < 1024)
                ? (AL + m15 * 1024 + k0 + q * 8)
                : (AR + m15 * 1024 + (k0 - 1024) + q * 8);
            bf16x8 av = *(const bf16x8*)ab;
            bf16x8 bv = *(const bf16x8*)(wlds + ts * 32768 + kb * 512 + lane * 8);
            acc = __builtin_amdgcn_mfma_f32_16x16x32_bf16(av, bv, acc, 0, 0, 0);
          }
          *(f32x4*)(red + (wv * 64 + lane) * 4) = acc;
          __syncthreads();
          if (wv == 0) {
            f32x4 a0 = *(f32x4*)(red + lane * 4);
            f32x4 a1 = *(f32x4*)(red + (64 + lane) * 4);
            f32x4 a2 = *(f32x4*)(red + (128 + lane) * 4);
            f32x4 a3 = *(f32x4*)(red + (192 + lane) * 4);
            f32x4 s = a0 + a1 + a2 + a3;
            int c = c0 + m15;
            float bias = BS[mk][layer * S_ + c];
            float* hm = layer ? h1 : h0;
#pragma unroll
            for (int r = 0; r < 4; r++) {
              int m = q * 4 + r;                 // D row = (lane>>4)*4 + reg (m89/m91)
              float p = s[r] + bias;
              int idx = m * S_ + c;
              if (mk == 0) {                      // z gate
                float zv = 1.f / (1.f + __expf(-p));
                (layer ? z1buf : z0buf)[idx] = zv;
              } else if (mk == 1) {               // r gate -> r*h (bf16, phase-B A input)
                float rv = 1.f / (1.f + __expf(-p));
                (layer ? rh1bf : rh0bf)[idx] = f2bf(rv * hm[idx]);
              } else {                            // n -> h update
                float nv = tanhf(p);
                float zv = (layer ? z1buf : z0buf)[idx];
                float hv = hm[idx];
                float hn = (1.f - zv) * hv + zv * nv;
                hm[idx] = hn;                     // fp32 master state
                unsigned short hb = f2bf(hn);
                (layer ? h1bf : h0bf)[idx] = hb;
                if (layer) hist[(size_t)t * B_ * S_ + idx] = hb;
              }
            }
          }
          __syncthreads();
        }
      }
      // grid barrier (monotonic counter; agent scope handles cross-XCD L2)
      epoch++;
      __syncthreads();
      if (tid == 0) {
        __hip_atomic_fetch_add(bar, 1u, __ATOMIC_ACQ_REL, __HIP_MEMORY_SCOPE_AGENT);
        unsigned target = epoch * (unsigned)NBLK;
        while (__hip_atomic_load(bar, __ATOMIC_ACQUIRE, __HIP_MEMORY_SCOPE_AGENT) < target)
          __builtin_amdgcn_s_sleep(2);
      }
      __syncthreads();
    }
  }
  // h_final tail: [2][16][1024] fp32
  for (int i = bid * NTHR + tid; i < 2 * B_ * S_; i += NBLK * NTHR) {
    int layer = i >> 14, rem = i & 16383;
    htail[i] = (layer ? h1 : h0)[rem];
  }
}

// --- output projection: C[4096][32000] = hist @ Wo + bo, fp32 out ---------
// 128x128 block tile, 4 waves in 2x2, 64x64 per wave, K=1024 in 32-chunks.
// Fragments direct from global: A rows 16B-contiguous, B pre-packed coalesced.
__global__ void __launch_bounds__(256) k_out(
    const unsigned short* __restrict__ hist, const unsigned short* __restrict__ pk,
    const float* __restrict__ bo, float* __restrict__ out) {
  int blk = blockIdx.x;
  int mt = blk & 31;                 // m fast -> 32 consecutive blocks share B (L2)
  int nt = blk >> 5;
  int wv = threadIdx.x >> 6, lane = threadIdx.x & 63;
  int wm = wv & 1, wn = wv >> 1;
  int m0 = mt * 128 + wm * 64;
  int n0 = nt * 128 + wn * 64;
  int q = lane >> 4, m15 = lane & 15;

  f32x4 zero = {0.f, 0.f, 0.f, 0.f};
  f32x4 acc[4][4];
#pragma unroll
  for (int i = 0; i < 4; i++)
#pragma unroll
    for (int j = 0; j < 4; j++) acc[i][j] = zero;

#pragma unroll 2
  for (int kb = 0; kb < 32; kb++) {
    bf16x8 a[4], b[4];
#pragma unroll
    for (int i = 0; i < 4; i++)
      a[i] = *(const bf16x8*)(hist + (size_t)(m0 + i * 16 + m15) * 1024 + kb * 32 + q * 8);
#pragma unroll
    for (int j = 0; j < 4; j++) {
      int nt16 = (n0 >> 4) + j;
      b[j] = *(const bf16x8*)(pk + ((size_t)(nt16 * 32 + kb) * 64 + lane) * 8);
    }
#pragma unroll
    for (int i = 0; i < 4; i++)
#pragma unroll
      for (int j = 0; j < 4; j++)
        acc[i][j] = __builtin_amdgcn_mfma_f32_16x16x32_bf16(a[i], b[j], acc[i][j], 0, 0, 0);
  }
#pragma unroll
  for (int i = 0; i < 4; i++) {
    int mbase = m0 + i * 16 + q * 4;
#pragma unroll
    for (int r = 0; r < 4; r++) {
      int m = mbase + r;
      int tt = m >> 4, bb = m & 15;
      float* orow = out + ((size_t)(bb * T_ + tt)) * V_;   // out[b][t][:]
#pragma unroll
      for (int j = 0; j < 4; j++) {
        int n = n0 + j * 16 + m15;
        orow[n] = acc[i][j][r] + bo[n];
      }
    }
  }
}

extern "C" void kernel_launch(void* const* d_in, const int* in_sizes, int n_in,
                              void* d_out, int out_size, void* d_ws, size_t ws_size,
                              hipStream_t stream) {
  const int*   x   = (const int*)d_in[0];
  const float* emb = (const float*)d_in[1];
  const float* Wz  = (const float*)d_in[2];
  const float* bz  = (const float*)d_in[3];
  const float* Wr  = (const float*)d_in[4];
  const float* br  = (const float*)d_in[5];
  const float* Wn  = (const float*)d_in[6];
  const float* bn  = (const float*)d_in[7];
  const float* Wo  = (const float*)d_in[8];
  const float* bo  = (const float*)d_in[9];
  float* out = (float*)d_out;

  // ws layout (bytes): pk 65,536,000 | embs 8,388,608 | hist 8,388,608 | state 393,472
  char* ws = (char*)d_ws;
  unsigned short* pk   = (unsigned short*)(ws);
  unsigned short* embs = (unsigned short*)(ws + 65536000);
  unsigned short* hist = (unsigned short*)(ws + 65536000 + 8388608);
  char* st = ws + 65536000 + 2 * 8388608;
  float* h0            = (float*)(st);
  float* h1            = (float*)(st + 65536);
  unsigned short* h0bf = (unsigned short*)(st + 131072);
  unsigned short* h1bf = (unsigned short*)(st + 163840);
  unsigned short* rh0bf= (unsigned short*)(st + 196608);
  unsigned short* rh1bf= (unsigned short*)(st + 229376);
  float* z0buf         = (float*)(st + 262144);
  float* z1buf         = (float*)(st + 327680);
  unsigned* bar        = (unsigned*)(st + 393216);

  // state + barrier counters must be zero every launch (ws is re-poisoned)
  hipMemsetAsync(st, 0, 393216 + 256, stream);
  k_pack_wo<<<16000, 256, 0, stream>>>(Wo, pk);
  k_embed<<<4096, 256, 0, stream>>>(x, emb, embs);
  (void)hipFuncSetAttribute((const void*)k_rnn,
                            hipFuncAttributeMaxDynamicSharedMemorySize, 135168);
  k_rnn<<<NBLK, NTHR, 135168, stream>>>(Wz, Wr, Wn, bz, br, bn, embs,
                                        h0, h1, h0bf, h1bf, rh0bf, rh1bf,
                                        z0buf, z1buf, hist, bar,
                                        out + 131072000LL);
  k_out<<<8000, 256, 0, stream>>>(hist, pk, bo, out);
}